// Round 6
// baseline (567.509 us; speedup 1.0000x reference)
//
#include <hip/hip_runtime.h>
#include <stdint.h>

typedef __bf16 bf16;
typedef __attribute__((ext_vector_type(8))) __bf16 bf16x8;
typedef __attribute__((ext_vector_type(4))) __bf16 bf16x4;
typedef __attribute__((ext_vector_type(4))) float f32x4;

#define DEVFN static __device__ __forceinline__

DEVFN void gload16(const bf16* g, char* l) {
  __builtin_amdgcn_global_load_lds(
      (const __attribute__((address_space(1))) void*)g,
      (__attribute__((address_space(3))) void*)l, 16, 0, 0);
}

DEVFN int swz(int row, int kb) { return row * 128 + (kb ^ ((row & 7) << 4)); }

// ---------------- prep: fp32 -> bf16 + weight transposes --------------------
__global__ __launch_bounds__(256) void prep_kernel(
    const float* __restrict__ x, const float* __restrict__ Wq,
    const float* __restrict__ Wk, const float* __restrict__ Wv,
    const float* __restrict__ Wp, bf16* __restrict__ xb,
    bf16* __restrict__ Wt, bf16* __restrict__ Wpt) {
  const int64_t tid = blockIdx.x * 256LL + threadIdx.x;
  const int64_t stride = (int64_t)gridDim.x * 256LL;
  for (int64_t i = tid; i < (8192LL * 512) / 4; i += stride) {
    float4 v = ((const float4*)x)[i];
    bf16x4 o = {(bf16)v.x, (bf16)v.y, (bf16)v.z, (bf16)v.w};
    ((bf16x4*)xb)[i] = o;
  }
  for (int64_t i = tid; i < 1536LL * 512; i += stride) {
    int c = (int)(i >> 9), k = (int)(i & 511);
    int wsel = c >> 9, cc = c & 511;
    const float* W = wsel == 0 ? Wq : (wsel == 1 ? Wk : Wv);
    Wt[i] = (bf16)W[k * 512 + cc];
  }
  for (int64_t i = tid; i < 512LL * 512; i += stride) {
    int c = (int)(i >> 9), k = (int)(i & 511);
    Wpt[i] = (bf16)Wp[k * 512 + c];
  }
}

// ---------------- shared 128x128 bf16 GEMM mainloop (K=512, BK=64) ----------
DEVFN void gemm_main(const bf16* __restrict__ A, const bf16* __restrict__ B,
                     int rowA0, int rowB0, char* sA, char* sB, f32x4 acc[4][4],
                     int wr, int wc, int lane, int w) {
#pragma unroll
  for (int m = 0; m < 4; m++)
#pragma unroll
    for (int n = 0; n < 4; n++) acc[m][n] = (f32x4){0.f, 0.f, 0.f, 0.f};
  const int lr = lane >> 3;
  const int kswz = 8 * ((lane & 7) ^ lr);
  for (int k0 = 0; k0 < 512; k0 += 64) {
#pragma unroll
    for (int j = 0; j < 4; j++) {
      const int c = w * 4 + j;
      gload16(A + (rowA0 + c * 8 + lr) * 512 + k0 + kswz, sA + c * 1024);
      gload16(B + (rowB0 + c * 8 + lr) * 512 + k0 + kswz, sB + c * 1024);
    }
    __syncthreads();
    bf16x8 af[4][2], bfv[4][2];
#pragma unroll
    for (int m = 0; m < 4; m++)
#pragma unroll
      for (int kk = 0; kk < 2; kk++) {
        af[m][kk] = *(const bf16x8*)(sA + swz(wr * 64 + m * 16 + (lane & 15),
                                              kk * 64 + (lane >> 4) * 16));
        bfv[m][kk] = *(const bf16x8*)(sB + swz(wc * 64 + m * 16 + (lane & 15),
                                               kk * 64 + (lane >> 4) * 16));
      }
#pragma unroll
    for (int m = 0; m < 4; m++)
#pragma unroll
      for (int n = 0; n < 4; n++)
#pragma unroll
        for (int kk = 0; kk < 2; kk++)
          acc[m][n] = __builtin_amdgcn_mfma_f32_16x16x32_bf16(
              af[m][kk], bfv[n][kk], acc[m][n], 0, 0, 0);
    __syncthreads();
  }
}

// ---------------- QKV projection ------------------------------------------
__global__ __launch_bounds__(256) void qkv_gemm(
    const bf16* __restrict__ xb, const bf16* __restrict__ Wt,
    const float* __restrict__ bq, const float* __restrict__ bk,
    const float* __restrict__ bv, bf16* __restrict__ Qb, bf16* __restrict__ Kb,
    bf16* __restrict__ Vt) {
  __shared__ __align__(128) char sA[16384];
  __shared__ __align__(128) char sB[16384];
  const int lane = threadIdx.x & 63, w = threadIdx.x >> 6;
  const int wr = w >> 1, wc = w & 1;
  const int rowA0 = blockIdx.y * 128;
  const int colB0 = blockIdx.x * 128;
  f32x4 acc[4][4];
  gemm_main(xb, Wt, rowA0, colB0, sA, sB, acc, wr, wc, lane, w);
  const int which = colB0 >> 9;
  const int cc0 = colB0 & 511;
  const float* bias = which == 0 ? bq : (which == 1 ? bk : bv);
#pragma unroll
  for (int m = 0; m < 4; m++)
#pragma unroll
    for (int n = 0; n < 4; n++)
#pragma unroll
      for (int r = 0; r < 4; r++) {
        int row = rowA0 + wr * 64 + m * 16 + (lane >> 4) * 4 + r;
        int col = cc0 + wc * 64 + n * 16 + (lane & 15);
        float v = acc[m][n][r] + bias[col];
        if (which == 0) {
          Qb[(int64_t)row * 512 + col] = (bf16)v;
        } else if (which == 1) {
          Kb[(int64_t)row * 512 + col] = (bf16)v;
        } else {
          int b = row >> 12, nn = row & 4095;
          int hh = col >> 6, e = col & 63;
          Vt[(((int64_t)(b * 8 + hh)) * 64 + e) * 4096 + nn] = (bf16)v;
        }
      }
}

// ---------------- output projection (fp32 out) ----------------------------
__global__ __launch_bounds__(256) void out_gemm(const bf16* __restrict__ Ob,
                                                const bf16* __restrict__ Wpt,
                                                const float* __restrict__ bp,
                                                float* __restrict__ out) {
  __shared__ __align__(128) char sA[16384];
  __shared__ __align__(128) char sB[16384];
  const int lane = threadIdx.x & 63, w = threadIdx.x >> 6;
  const int wr = w >> 1, wc = w & 1;
  const int rowA0 = blockIdx.y * 128;
  const int colB0 = blockIdx.x * 128;
  f32x4 acc[4][4];
  gemm_main(Ob, Wpt, rowA0, colB0, sA, sB, acc, wr, wc, lane, w);
#pragma unroll
  for (int m = 0; m < 4; m++)
#pragma unroll
    for (int n = 0; n < 4; n++)
#pragma unroll
      for (int r = 0; r < 4; r++) {
        int row = rowA0 + wr * 64 + m * 16 + (lane >> 4) * 4 + r;
        int col = colB0 + wc * 64 + n * 16 + (lane & 15);
        out[(int64_t)row * 512 + col] = acc[m][n][r] + bp[col];
      }
}

// ---------------- fused flash attention, barrier-free swapped-QK^T ---------
// grid 1024 flat (XCD-aware decode), 256 thr = 4 fully independent waves
// (no __syncthreads anywhere). Wave = one head, 16 q-rows. Lane owns q-row
// q0+(lane&15). ALL loop inputs (K, V, coords) register-prefetched one full
// tile ahead so no global-load latency sits on the critical path.
__global__ __launch_bounds__(256) void attn_kernel(
    const bf16* __restrict__ Qb, const bf16* __restrict__ Kb,
    const bf16* __restrict__ Vt, const float* __restrict__ coords,
    const float* __restrict__ slopes, bf16* __restrict__ Ob) {
  __shared__ __align__(128) char sP[4][2048];  // per-wave P tile, wave-private

  const int tid = threadIdx.x;
  const int lane = tid & 63, w = tid >> 6;
  const int c = lane & 15, g = lane >> 4;

  // XCD-aware decode: XCD pair {2k,2k+1} serves one (b,hg) combo (4MB K+V=L2)
  const int id = blockIdx.x;            // 0..1023
  const int xcd = id & 7, j = id >> 3;
  const int combo = xcd >> 1;           // 0..3
  const int b = combo >> 1, hg = combo & 1;
  const int qt = j | ((xcd & 1) << 7);  // 0..255
  const int q0 = qt * 16;
  const int h = hg * 4 + w;

  const float LOG2E = 1.4426950408889634f;
  const float c1 = 0.125f * LOG2E;
  const float negsl2 = -slopes[h] * LOG2E;

  // Q fragments (B-operand of swapped QK^T): lane holds Q[q=c][hd=g*8+j]
  bf16x8 aq[2];
  {
    int64_t base = ((int64_t)(b * 4096 + q0 + c)) * 512 + h * 64 + g * 8;
    aq[0] = *(const bf16x8*)(Qb + base);
    aq[1] = *(const bf16x8*)(Qb + base + 32);
  }
  const float2* cb2 = (const float2*)coords + (int64_t)b * 4096;
  float qcx, qcy;
  {
    float2 qc = cb2[q0 + c];
    qcx = qc.x;
    qcy = qc.y;
  }

  bf16x8 ones;
#pragma unroll
  for (int jj = 0; jj < 8; jj++) ones[jj] = (bf16)1.0f;

  float m2 = -1e30f;  // running max for q=c (one row per lane)
  f32x4 o[4], osum;
#pragma unroll
  for (int n = 0; n < 4; n++) o[n] = (f32x4){0.f, 0.f, 0.f, 0.f};
  osum = (f32x4){0.f, 0.f, 0.f, 0.f};

  const bf16* Kp = Kb + (int64_t)b * 4096 * 512 + h * 64;
  const bf16* Vp = Vt + (int64_t)(b * 8 + h) * 64 * 4096;

  bf16x8 kf[4][2], vf[4][2];
  float4 cc[8];  // next tile's kv coords (16 coords = 8 float4)
#define LOADK(KV)                                                         \
  {                                                                       \
    _Pragma("unroll") for (int t = 0; t < 4; t++) _Pragma("unroll") for ( \
        int kk = 0; kk < 2; kk++) kf[t][kk] =                             \
        *(const bf16x8*)(Kp + (int)(((KV) + t * 16 + c) * 512 +           \
                                    kk * 32 + g * 8));                    \
  }
#define LOADV(KV)                                                         \
  {                                                                       \
    _Pragma("unroll") for (int n = 0; n < 4; n++) _Pragma("unroll") for ( \
        int kk = 0; kk < 2; kk++) vf[n][kk] =                             \
        *(const bf16x8*)(Vp + (int)((n * 16 + c) * 4096 + (KV) +          \
                                    kk * 32 + g * 8));                    \
  }
#define LOADC(KV)                                                          \
  {                                                                        \
    _Pragma("unroll") for (int tp = 0; tp < 2; tp++) {                     \
      cc[4 * tp + 0] = *(const float4*)(cb2 + (KV) + (2 * tp) * 16 + g * 4);   \
      cc[4 * tp + 1] =                                                     \
          *(const float4*)(cb2 + (KV) + (2 * tp) * 16 + g * 4 + 2);        \
      cc[4 * tp + 2] =                                                     \
          *(const float4*)(cb2 + (KV) + (2 * tp + 1) * 16 + g * 4);        \
      cc[4 * tp + 3] =                                                     \
          *(const float4*)(cb2 + (KV) + (2 * tp + 1) * 16 + g * 4 + 2);    \
    }                                                                      \
  }

  LOADK(0);
  LOADV(0);
  LOADC(0);

  char* pw = (char*)sP[w];
  const int pmask = (c & 7) << 4;
  for (int i = 0; i < 64; i++) {
    // S^T = (K Q^T): lane holds q=c, kv=16t+4g+r
    float s[4][4];
#pragma unroll
    for (int t = 0; t < 4; t++) {
      f32x4 sa = (f32x4){0.f, 0.f, 0.f, 0.f};
      sa = __builtin_amdgcn_mfma_f32_16x16x32_bf16(kf[t][0], aq[0], sa, 0, 0, 0);
      sa = __builtin_amdgcn_mfma_f32_16x16x32_bf16(kf[t][1], aq[1], sa, 0, 0, 0);
#pragma unroll
      for (int r = 0; r < 4; r++) s[t][r] = sa[r];
    }
    if (i + 1 < 64) LOADK((i + 1) * 64);

    // in-register bias from coords prefetched one tile ahead (regs cc[])
#pragma unroll
    for (int tp = 0; tp < 2; tp++) {
      float4 A0 = cc[4 * tp + 0], A1 = cc[4 * tp + 1];
      float4 B0 = cc[4 * tp + 2], B1 = cc[4 * tp + 3];
      float dx, dy;
#define DIST1(T, R, CX, CY)                                             \
  dx = qcx - (CX);                                                      \
  dy = qcy - (CY);                                                      \
  s[T][R] = __builtin_fmaf(s[T][R], c1,                                 \
                           __builtin_amdgcn_sqrtf(dx * dx + dy * dy) *  \
                               negsl2);
      DIST1(2 * tp, 0, A0.x, A0.y)
      DIST1(2 * tp, 1, A0.z, A0.w)
      DIST1(2 * tp, 2, A1.x, A1.y)
      DIST1(2 * tp, 3, A1.z, A1.w)
      DIST1(2 * tp + 1, 0, B0.x, B0.y)
      DIST1(2 * tp + 1, 1, B0.z, B0.w)
      DIST1(2 * tp + 1, 2, B1.x, B1.y)
      DIST1(2 * tp + 1, 3, B1.z, B1.w)
#undef DIST1
    }
    if (i + 1 < 64) LOADC((i + 1) * 64);

    // deferred online max (THR=8 base-2); row q=c lives on 4 g-lanes
    float lm = fmaxf(fmaxf(fmaxf(s[0][0], s[0][1]), fmaxf(s[0][2], s[0][3])),
                     fmaxf(fmaxf(s[1][0], s[1][1]), fmaxf(s[1][2], s[1][3])));
    lm = fmaxf(lm,
               fmaxf(fmaxf(fmaxf(s[2][0], s[2][1]), fmaxf(s[2][2], s[2][3])),
                     fmaxf(fmaxf(s[3][0], s[3][1]), fmaxf(s[3][2], s[3][3]))));
    lm = fmaxf(lm, __shfl_xor(lm, 16));
    lm = fmaxf(lm, __shfl_xor(lm, 32));
    if (__any(lm > m2 + 8.f)) {
      float nm = fmaxf(m2, lm);
      float sc = __builtin_amdgcn_exp2f(m2 - nm);
      m2 = nm;
      float scr[4];
#pragma unroll
      for (int r = 0; r < 4; r++)
        scr[r] = __shfl(sc, (lane & 48) | (4 * g + r));
#pragma unroll
      for (int n = 0; n < 4; n++)
#pragma unroll
        for (int r = 0; r < 4; r++) o[n][r] *= scr[r];
#pragma unroll
      for (int r = 0; r < 4; r++) osum[r] *= scr[r];
    }

    // P = exp2(s - m2): kv contiguous along r -> one b64 store per t
#pragma unroll
    for (int t = 0; t < 4; t++) {
      bf16x4 pv = {(bf16)__builtin_amdgcn_exp2f(s[t][0] - m2),
                   (bf16)__builtin_amdgcn_exp2f(s[t][1] - m2),
                   (bf16)__builtin_amdgcn_exp2f(s[t][2] - m2),
                   (bf16)__builtin_amdgcn_exp2f(s[t][3] - m2)};
      *(bf16x4*)(pw + c * 128 + ((32 * t + 8 * g) ^ pmask)) = pv;
    }
    bf16x8 pa0 = *(const bf16x8*)(pw + c * 128 + ((16 * g) ^ pmask));
    bf16x8 pa1 = *(const bf16x8*)(pw + c * 128 + ((64 + 16 * g) ^ pmask));
#pragma unroll
    for (int n = 0; n < 4; n++) {
      o[n] = __builtin_amdgcn_mfma_f32_16x16x32_bf16(pa0, vf[n][0], o[n], 0, 0, 0);
      o[n] = __builtin_amdgcn_mfma_f32_16x16x32_bf16(pa1, vf[n][1], o[n], 0, 0, 0);
    }
    osum = __builtin_amdgcn_mfma_f32_16x16x32_bf16(pa0, ones, osum, 0, 0, 0);
    osum = __builtin_amdgcn_mfma_f32_16x16x32_bf16(pa1, ones, osum, 0, 0, 0);
    if (i + 1 < 64) LOADV((i + 1) * 64);
  }

  // epilogue: normalize, store [b,n,d] bf16 (rows q = 4g+r)
#pragma unroll
  for (int r = 0; r < 4; r++) {
    float inv = 1.f / osum[r];
    int64_t row = (int64_t)b * 4096 + q0 + g * 4 + r;
#pragma unroll
    for (int n = 0; n < 4; n++)
      Ob[row * 512 + h * 64 + n * 16 + c] = (bf16)(o[n][r] * inv);
  }
}

// ---------------- launch ---------------------------------------------------
extern "C" void kernel_launch(void* const* d_in, const int* in_sizes, int n_in,
                              void* d_out, int out_size, void* d_ws,
                              size_t ws_size, hipStream_t stream) {
  const float* x = (const float*)d_in[0];
  const float* coords = (const float*)d_in[1];
  const float* Wq = (const float*)d_in[2];
  const float* bq = (const float*)d_in[3];
  const float* Wk = (const float*)d_in[4];
  const float* bk = (const float*)d_in[5];
  const float* Wv = (const float*)d_in[6];
  const float* bv = (const float*)d_in[7];
  const float* Wp = (const float*)d_in[8];
  const float* bp = (const float*)d_in[9];
  const float* slopes = (const float*)d_in[10];

  char* ws = (char*)d_ws;
  bf16* xb = (bf16*)(ws);
  bf16* Wt = (bf16*)(ws + 8388608);
  bf16* Wpt = (bf16*)(ws + 9961472);
  bf16* Qb = (bf16*)(ws + 10485760);
  bf16* Kb = (bf16*)(ws + 18874368);
  bf16* Vt = (bf16*)(ws + 27262976);
  bf16* Ob = (bf16*)(ws + 35651584);

  hipLaunchKernelGGL(prep_kernel, dim3(1024), dim3(256), 0, stream, x, Wq, Wk,
                     Wv, Wp, xb, Wt, Wpt);
  hipLaunchKernelGGL(qkv_gemm, dim3(12, 64), dim3(256), 0, stream, xb, Wt, bq,
                     bk, bv, Qb, Kb, Vt);
  hipLaunchKernelGGL(attn_kernel, dim3(1024), dim3(256), 0, stream, Qb, Kb,
                     Vt, coords, slopes, Ob);
  hipLaunchKernelGGL(out_gemm, dim3(4, 64), dim3(256), 0, stream, Ob, Wpt, bp,
                     (float*)d_out);
}

// Round 7
// 248.701 us; speedup vs baseline: 2.2819x; 2.2819x over previous
//
#include <hip/hip_runtime.h>
#include <stdint.h>

typedef __bf16 bf16;
typedef __attribute__((ext_vector_type(8))) __bf16 bf16x8;
typedef __attribute__((ext_vector_type(4))) __bf16 bf16x4;
typedef __attribute__((ext_vector_type(4))) float f32x4;

#define DEVFN static __device__ __forceinline__

DEVFN void gload16(const bf16* g, char* l) {
  __builtin_amdgcn_global_load_lds(
      (const __attribute__((address_space(1))) void*)g,
      (__attribute__((address_space(3))) void*)l, 16, 0, 0);
}
DEVFN void gload4(const float* g, char* l) {
  __builtin_amdgcn_global_load_lds(
      (const __attribute__((address_space(1))) void*)g,
      (__attribute__((address_space(3))) void*)l, 4, 0, 0);
}

DEVFN int swz(int row, int kb) { return row * 128 + (kb ^ ((row & 7) << 4)); }

// ---------------- prep: fp32 -> bf16 + weight transposes --------------------
__global__ __launch_bounds__(256) void prep_kernel(
    const float* __restrict__ x, const float* __restrict__ Wq,
    const float* __restrict__ Wk, const float* __restrict__ Wv,
    const float* __restrict__ Wp, bf16* __restrict__ xb,
    bf16* __restrict__ Wt, bf16* __restrict__ Wpt) {
  const int64_t tid = blockIdx.x * 256LL + threadIdx.x;
  const int64_t stride = (int64_t)gridDim.x * 256LL;
  for (int64_t i = tid; i < (8192LL * 512) / 4; i += stride) {
    float4 v = ((const float4*)x)[i];
    bf16x4 o = {(bf16)v.x, (bf16)v.y, (bf16)v.z, (bf16)v.w};
    ((bf16x4*)xb)[i] = o;
  }
  for (int64_t i = tid; i < 1536LL * 512; i += stride) {
    int c = (int)(i >> 9), k = (int)(i & 511);
    int wsel = c >> 9, cc = c & 511;
    const float* W = wsel == 0 ? Wq : (wsel == 1 ? Wk : Wv);
    Wt[i] = (bf16)W[k * 512 + cc];
  }
  for (int64_t i = tid; i < 512LL * 512; i += stride) {
    int c = (int)(i >> 9), k = (int)(i & 511);
    Wpt[i] = (bf16)Wp[k * 512 + c];
  }
}

// ---------------- shared 128x128 bf16 GEMM mainloop (K=512, BK=64) ----------
DEVFN void gemm_main(const bf16* __restrict__ A, const bf16* __restrict__ B,
                     int rowA0, int rowB0, char* sA, char* sB, f32x4 acc[4][4],
                     int wr, int wc, int lane, int w) {
#pragma unroll
  for (int m = 0; m < 4; m++)
#pragma unroll
    for (int n = 0; n < 4; n++) acc[m][n] = (f32x4){0.f, 0.f, 0.f, 0.f};
  const int lr = lane >> 3;
  const int kswz = 8 * ((lane & 7) ^ lr);
  for (int k0 = 0; k0 < 512; k0 += 64) {
#pragma unroll
    for (int j = 0; j < 4; j++) {
      const int c = w * 4 + j;
      gload16(A + (rowA0 + c * 8 + lr) * 512 + k0 + kswz, sA + c * 1024);
      gload16(B + (rowB0 + c * 8 + lr) * 512 + k0 + kswz, sB + c * 1024);
    }
    __syncthreads();
    bf16x8 af[4][2], bfv[4][2];
#pragma unroll
    for (int m = 0; m < 4; m++)
#pragma unroll
      for (int kk = 0; kk < 2; kk++) {
        af[m][kk] = *(const bf16x8*)(sA + swz(wr * 64 + m * 16 + (lane & 15),
                                              kk * 64 + (lane >> 4) * 16));
        bfv[m][kk] = *(const bf16x8*)(sB + swz(wc * 64 + m * 16 + (lane & 15),
                                               kk * 64 + (lane >> 4) * 16));
      }
#pragma unroll
    for (int m = 0; m < 4; m++)
#pragma unroll
      for (int n = 0; n < 4; n++)
#pragma unroll
        for (int kk = 0; kk < 2; kk++)
          acc[m][n] = __builtin_amdgcn_mfma_f32_16x16x32_bf16(
              af[m][kk], bfv[n][kk], acc[m][n], 0, 0, 0);
    __syncthreads();
  }
}

// ---------------- QKV projection ------------------------------------------
__global__ __launch_bounds__(256) void qkv_gemm(
    const bf16* __restrict__ xb, const bf16* __restrict__ Wt,
    const float* __restrict__ bq, const float* __restrict__ bk,
    const float* __restrict__ bv, bf16* __restrict__ Qb, bf16* __restrict__ Kb,
    bf16* __restrict__ Vt) {
  __shared__ __align__(128) char sA[16384];
  __shared__ __align__(128) char sB[16384];
  const int lane = threadIdx.x & 63, w = threadIdx.x >> 6;
  const int wr = w >> 1, wc = w & 1;
  const int rowA0 = blockIdx.y * 128;
  const int colB0 = blockIdx.x * 128;
  f32x4 acc[4][4];
  gemm_main(xb, Wt, rowA0, colB0, sA, sB, acc, wr, wc, lane, w);
  const int which = colB0 >> 9;
  const int cc0 = colB0 & 511;
  const float* bias = which == 0 ? bq : (which == 1 ? bk : bv);
#pragma unroll
  for (int m = 0; m < 4; m++)
#pragma unroll
    for (int n = 0; n < 4; n++)
#pragma unroll
      for (int r = 0; r < 4; r++) {
        int row = rowA0 + wr * 64 + m * 16 + (lane >> 4) * 4 + r;
        int col = cc0 + wc * 64 + n * 16 + (lane & 15);
        float v = acc[m][n][r] + bias[col];
        if (which == 0) {
          Qb[(int64_t)row * 512 + col] = (bf16)v;
        } else if (which == 1) {
          Kb[(int64_t)row * 512 + col] = (bf16)v;
        } else {
          int b = row >> 12, nn = row & 4095;
          int hh = col >> 6, e = col & 63;
          Vt[(((int64_t)(b * 8 + hh)) * 64 + e) * 4096 + nn] = (bf16)v;
        }
      }
}

// ---------------- output projection (fp32 out) ----------------------------
__global__ __launch_bounds__(256) void out_gemm(const bf16* __restrict__ Ob,
                                                const bf16* __restrict__ Wpt,
                                                const float* __restrict__ bp,
                                                float* __restrict__ out) {
  __shared__ __align__(128) char sA[16384];
  __shared__ __align__(128) char sB[16384];
  const int lane = threadIdx.x & 63, w = threadIdx.x >> 6;
  const int wr = w >> 1, wc = w & 1;
  const int rowA0 = blockIdx.y * 128;
  const int colB0 = blockIdx.x * 128;
  f32x4 acc[4][4];
  gemm_main(Ob, Wpt, rowA0, colB0, sA, sB, acc, wr, wc, lane, w);
#pragma unroll
  for (int m = 0; m < 4; m++)
#pragma unroll
    for (int n = 0; n < 4; n++)
#pragma unroll
      for (int r = 0; r < 4; r++) {
        int row = rowA0 + wr * 64 + m * 16 + (lane >> 4) * 4 + r;
        int col = colB0 + wc * 64 + n * 16 + (lane & 15);
        out[(int64_t)row * 512 + col] = acc[m][n][r] + bp[col];
      }
}

// ---------------- fused flash attention: async-LDS 2-phase pipeline --------
// 512 thr = 8 waves = 2 heads x 4 q-subwaves (16 q-rows each; q-tile 64).
// KVBLK=32, K/V/coords double-buffered in LDS via global_load_lds (zero-VGPR
// prefetch); one barrier per tile; stage(i+1) issued before compute(i).
// Swapped QK^T: lane owns q-row = c; bias dist in-register.
// grid 512: combo=(id&7) -> one XCD holds that (b,head-pair) K+V in its L2.
__global__ __launch_bounds__(512) void attn_kernel(
    const bf16* __restrict__ Qb, const bf16* __restrict__ Kb,
    const bf16* __restrict__ Vt, const float* __restrict__ coords,
    const float* __restrict__ slopes, bf16* __restrict__ Ob) {
  __shared__ __align__(128) char sK[2 * 8192];   // [buf][32 kv][256B: 2 heads]
  __shared__ __align__(128) char sV[2 * 10240];  // [buf][2 heads][64e][80B]
  __shared__ __align__(128) char sC[2 * 256];    // [buf][32 kv float2]
  __shared__ __align__(128) char sP[8 * 1024];   // per-wave P [16q][64B]

  const int tid = threadIdx.x;
  const int lane = tid & 63, w = tid >> 6;
  const int c = lane & 15, g = lane >> 4;

  const int id = blockIdx.x;       // 0..511
  const int combo = id & 7;        // -> XCD
  const int qt = id >> 3;          // 0..63
  const int b = combo >> 2, hp = combo & 3;  // head-pair 0..3
  const int q0 = qt * 64;
  const int qsub = w >> 1;         // 0..3
  const int hl = w & 1;            // head within pair
  const int h = hp * 2 + hl;
  const int qw = q0 + qsub * 16;
  const int bO = b * 4096;

  const float LOG2E = 1.4426950408889634f;
  const float c1 = 0.125f * LOG2E;
  const float negsl2 = -slopes[h] * LOG2E;

  // Q fragments (B-operand of swapped QK^T): lane holds Q[q=c][hd=g*8+j]
  bf16x8 aq[2];
  {
    int64_t base = ((int64_t)(bO + qw + c)) * 512 + h * 64 + g * 8;
    aq[0] = *(const bf16x8*)(Qb + base);
    aq[1] = *(const bf16x8*)(Qb + base + 32);
  }
  const float* cbf = coords + (int64_t)bO * 2;
  float qcx, qcy;
  {
    float2 qc = ((const float2*)cbf)[qw + c];
    qcx = qc.x;
    qcy = qc.y;
  }

  bf16x8 ones;
#pragma unroll
  for (int jj = 0; jj < 8; jj++) ones[jj] = (bf16)1.0f;

  float m2 = -1e30f;
  f32x4 o[4], osum;
#pragma unroll
  for (int n = 0; n < 4; n++) o[n] = (f32x4){0.f, 0.f, 0.f, 0.f};
  osum = (f32x4){0.f, 0.f, 0.f, 0.f};

  const bf16* Vbase = Vt + (int64_t)(b * 8 + hp * 2) * 64 * 4096;

  // -------- staging (zero-VGPR async) --------
  // K: [32 kv][16 granules of 16B], read-swizzle phys=log^(row&7) ->
  //    pre-swizzled global source. 8 x 1KB instrs, one per wave.
  // V: per head [64 e][80B rows: 64B data + 16B pad]; 5KB/head; 10 instrs.
  // coords: 256B, one gload4 by wave 7.
  const int krr = w * 4 + (lane >> 4);
  const int kgs = (lane & 15) ^ (krr & 7);
  auto vstage = [&](int j, int kv0, char* dstb) {
    const int hj = j >= 5 ? 1 : 0;
    const int cj = j - hj * 5;
    const int G = cj * 64 + lane;          // 16B-granule id in head region
    const int row = (G * 52429) >> 18;     // G/5
    int gr = G - row * 5;
    if (gr > 3) gr = 0;                    // pad lane: harmless dup
    gload16(Vbase + (int64_t)hj * 262144 + row * 4096 + kv0 + gr * 8,
            dstb + hj * 5120 + cj * 1024);
  };
  auto STAGE = [&](int tile, int bb) {
    const int kv0 = tile * 32;
    gload16(Kb + (int64_t)(bO + kv0 + krr) * 512 + hp * 128 + kgs * 8,
            sK + bb * 8192 + w * 1024);
    vstage(w, kv0, sV + bb * 10240);
    if (w < 2) vstage(8 + w, kv0, sV + bb * 10240);
    if (w == 7) gload4(cbf + kv0 * 2 + lane, sC + bb * 256);
  };

  STAGE(0, 0);
  __syncthreads();

  char* pwv = sP + w * 1024;
  for (int tt = 0; tt < 128; ++tt) {
    const int bb = tt & 1;
    if (tt + 1 < 128) STAGE(tt + 1, bb ^ 1);

    const char* kb = sK + bb * 8192;
    const char* vb = sV + bb * 10240 + hl * 5120;
    const char* cbuf = sC + bb * 256;

    // S^T = (K Q^T): lane holds q=c, kv = 16t+4g+r, t in {0,1}
    bf16x8 kf[2][2];
#pragma unroll
    for (int t = 0; t < 2; t++)
#pragma unroll
      for (int kk = 0; kk < 2; kk++) {
        const int row = t * 16 + c;
        const int pg = (hl * 8 + kk * 4 + g) ^ (c & 7);
        kf[t][kk] = *(const bf16x8*)(kb + row * 256 + pg * 16);
      }
    float s[2][4];
#pragma unroll
    for (int t = 0; t < 2; t++) {
      f32x4 sa = (f32x4){0.f, 0.f, 0.f, 0.f};
      sa = __builtin_amdgcn_mfma_f32_16x16x32_bf16(kf[t][0], aq[0], sa, 0, 0, 0);
      sa = __builtin_amdgcn_mfma_f32_16x16x32_bf16(kf[t][1], aq[1], sa, 0, 0, 0);
#pragma unroll
      for (int r = 0; r < 4; r++) s[t][r] = sa[r];
    }

    // in-register bias from LDS-staged coords (broadcast reads)
#pragma unroll
    for (int t = 0; t < 2; t++) {
      f32x4 ca = *(const f32x4*)(cbuf + 128 * t + 32 * g);
      f32x4 cb = *(const f32x4*)(cbuf + 128 * t + 32 * g + 16);
      float dx, dy;
#define DIST1(T, R, CX, CY)                                             \
  dx = qcx - (CX);                                                      \
  dy = qcy - (CY);                                                      \
  s[T][R] = __builtin_fmaf(s[T][R], c1,                                 \
                           __builtin_amdgcn_sqrtf(dx * dx + dy * dy) *  \
                               negsl2);
      DIST1(t, 0, ca[0], ca[1])
      DIST1(t, 1, ca[2], ca[3])
      DIST1(t, 2, cb[0], cb[1])
      DIST1(t, 3, cb[2], cb[3])
#undef DIST1
    }

    // deferred online max (THR=8 base-2); row q=c lives on 4 g-lanes
    float lm = fmaxf(fmaxf(fmaxf(s[0][0], s[0][1]), fmaxf(s[0][2], s[0][3])),
                     fmaxf(fmaxf(s[1][0], s[1][1]), fmaxf(s[1][2], s[1][3])));
    lm = fmaxf(lm, __shfl_xor(lm, 16));
    lm = fmaxf(lm, __shfl_xor(lm, 32));
    if (__any(lm > m2 + 8.f)) {
      float nm = fmaxf(m2, lm);
      float sc = __builtin_amdgcn_exp2f(m2 - nm);
      m2 = nm;
      float scr[4];
#pragma unroll
      for (int r = 0; r < 4; r++)
        scr[r] = __shfl(sc, (lane & 48) | (4 * g + r));
#pragma unroll
      for (int n = 0; n < 4; n++)
#pragma unroll
        for (int r = 0; r < 4; r++) o[n][r] *= scr[r];
#pragma unroll
      for (int r = 0; r < 4; r++) osum[r] *= scr[r];
    }

    // P pack: [16q][32kv] bf16, 64B rows, 16B-granule XOR (c&3)
#pragma unroll
    for (int t = 0; t < 2; t++) {
      bf16x4 pv = {(bf16)__builtin_amdgcn_exp2f(s[t][0] - m2),
                   (bf16)__builtin_amdgcn_exp2f(s[t][1] - m2),
                   (bf16)__builtin_amdgcn_exp2f(s[t][2] - m2),
                   (bf16)__builtin_amdgcn_exp2f(s[t][3] - m2)};
      const int phys = (2 * t + (g >> 1)) ^ (c & 3);
      *(bf16x4*)(pwv + c * 64 + phys * 16 + (g & 1) * 8) = pv;
    }
    bf16x8 pa = *(const bf16x8*)(pwv + c * 64 + ((g ^ (c & 3)) * 16));

    // PV + row-sum via ones-MFMA
#pragma unroll
    for (int n = 0; n < 4; n++) {
      bf16x8 vf = *(const bf16x8*)(vb + (n * 16 + c) * 80 + g * 16);
      o[n] = __builtin_amdgcn_mfma_f32_16x16x32_bf16(pa, vf, o[n], 0, 0, 0);
    }
    osum = __builtin_amdgcn_mfma_f32_16x16x32_bf16(pa, ones, osum, 0, 0, 0);

    __syncthreads();
  }

  // epilogue: normalize, store [b,n,d] bf16 (rows q = 4g+r)
#pragma unroll
  for (int r = 0; r < 4; r++) {
    float inv = 1.f / osum[r];
    int64_t row = (int64_t)bO + qw + g * 4 + r;
#pragma unroll
    for (int n = 0; n < 4; n++)
      Ob[row * 512 + h * 64 + n * 16 + c] = (bf16)(o[n][r] * inv);
  }
}

// ---------------- launch ---------------------------------------------------
extern "C" void kernel_launch(void* const* d_in, const int* in_sizes, int n_in,
                              void* d_out, int out_size, void* d_ws,
                              size_t ws_size, hipStream_t stream) {
  const float* x = (const float*)d_in[0];
  const float* coords = (const float*)d_in[1];
  const float* Wq = (const float*)d_in[2];
  const float* bq = (const float*)d_in[3];
  const float* Wk = (const float*)d_in[4];
  const float* bk = (const float*)d_in[5];
  const float* Wv = (const float*)d_in[6];
  const float* bv = (const float*)d_in[7];
  const float* Wp = (const float*)d_in[8];
  const float* bp = (const float*)d_in[9];
  const float* slopes = (const float*)d_in[10];

  char* ws = (char*)d_ws;
  bf16* xb = (bf16*)(ws);
  bf16* Wt = (bf16*)(ws + 8388608);
  bf16* Wpt = (bf16*)(ws + 9961472);
  bf16* Qb = (bf16*)(ws + 10485760);
  bf16* Kb = (bf16*)(ws + 18874368);
  bf16* Vt = (bf16*)(ws + 27262976);
  bf16* Ob = (bf16*)(ws + 35651584);

  hipLaunchKernelGGL(prep_kernel, dim3(1024), dim3(256), 0, stream, x, Wq, Wk,
                     Wv, Wp, xb, Wt, Wpt);
  hipLaunchKernelGGL(qkv_gemm, dim3(12, 64), dim3(256), 0, stream, xb, Wt, bq,
                     bk, bv, Qb, Kb, Vt);
  hipLaunchKernelGGL(attn_kernel, dim3(512), dim3(512), 0, stream, Qb, Kb,
                     Vt, coords, slopes, Ob);
  hipLaunchKernelGGL(out_gemm, dim3(4, 64), dim3(256), 0, stream, Ob, Wpt, bp,
                     (float*)d_out);
}

// Round 8
// 235.998 us; speedup vs baseline: 2.4047x; 1.0538x over previous
//
#include <hip/hip_runtime.h>
#include <stdint.h>

typedef __bf16 bf16;
typedef __attribute__((ext_vector_type(8))) __bf16 bf16x8;
typedef __attribute__((ext_vector_type(4))) __bf16 bf16x4;
typedef __attribute__((ext_vector_type(4))) float f32x4;

#define DEVFN static __device__ __forceinline__

DEVFN void gload16(const bf16* g, char* l) {
  __builtin_amdgcn_global_load_lds(
      (const __attribute__((address_space(1))) void*)g,
      (__attribute__((address_space(3))) void*)l, 16, 0, 0);
}
DEVFN void gload4(const float* g, char* l) {
  __builtin_amdgcn_global_load_lds(
      (const __attribute__((address_space(1))) void*)g,
      (__attribute__((address_space(3))) void*)l, 4, 0, 0);
}

DEVFN int swz(int row, int kb) { return row * 128 + (kb ^ ((row & 7) << 4)); }

// ---------------- prep: fp32 -> bf16 + weight transposes --------------------
__global__ __launch_bounds__(256) void prep_kernel(
    const float* __restrict__ x, const float* __restrict__ Wq,
    const float* __restrict__ Wk, const float* __restrict__ Wv,
    const float* __restrict__ Wp, bf16* __restrict__ xb,
    bf16* __restrict__ Wt, bf16* __restrict__ Wpt) {
  const int64_t tid = blockIdx.x * 256LL + threadIdx.x;
  const int64_t stride = (int64_t)gridDim.x * 256LL;
  for (int64_t i = tid; i < (8192LL * 512) / 4; i += stride) {
    float4 v = ((const float4*)x)[i];
    bf16x4 o = {(bf16)v.x, (bf16)v.y, (bf16)v.z, (bf16)v.w};
    ((bf16x4*)xb)[i] = o;
  }
  for (int64_t i = tid; i < 1536LL * 512; i += stride) {
    int c = (int)(i >> 9), k = (int)(i & 511);
    int wsel = c >> 9, cc = c & 511;
    const float* W = wsel == 0 ? Wq : (wsel == 1 ? Wk : Wv);
    Wt[i] = (bf16)W[k * 512 + cc];
  }
  for (int64_t i = tid; i < 512LL * 512; i += stride) {
    int c = (int)(i >> 9), k = (int)(i & 511);
    Wpt[i] = (bf16)Wp[k * 512 + c];
  }
}

// ---------------- shared 128x128 bf16 GEMM mainloop (K=512, BK=64) ----------
DEVFN void gemm_main(const bf16* __restrict__ A, const bf16* __restrict__ B,
                     int rowA0, int rowB0, char* sA, char* sB, f32x4 acc[4][4],
                     int wr, int wc, int lane, int w) {
#pragma unroll
  for (int m = 0; m < 4; m++)
#pragma unroll
    for (int n = 0; n < 4; n++) acc[m][n] = (f32x4){0.f, 0.f, 0.f, 0.f};
  const int lr = lane >> 3;
  const int kswz = 8 * ((lane & 7) ^ lr);
  for (int k0 = 0; k0 < 512; k0 += 64) {
#pragma unroll
    for (int j = 0; j < 4; j++) {
      const int c = w * 4 + j;
      gload16(A + (rowA0 + c * 8 + lr) * 512 + k0 + kswz, sA + c * 1024);
      gload16(B + (rowB0 + c * 8 + lr) * 512 + k0 + kswz, sB + c * 1024);
    }
    __syncthreads();
    bf16x8 af[4][2], bfv[4][2];
#pragma unroll
    for (int m = 0; m < 4; m++)
#pragma unroll
      for (int kk = 0; kk < 2; kk++) {
        af[m][kk] = *(const bf16x8*)(sA + swz(wr * 64 + m * 16 + (lane & 15),
                                              kk * 64 + (lane >> 4) * 16));
        bfv[m][kk] = *(const bf16x8*)(sB + swz(wc * 64 + m * 16 + (lane & 15),
                                               kk * 64 + (lane >> 4) * 16));
      }
#pragma unroll
    for (int m = 0; m < 4; m++)
#pragma unroll
      for (int n = 0; n < 4; n++)
#pragma unroll
        for (int kk = 0; kk < 2; kk++)
          acc[m][n] = __builtin_amdgcn_mfma_f32_16x16x32_bf16(
              af[m][kk], bfv[n][kk], acc[m][n], 0, 0, 0);
    __syncthreads();
  }
}

// ---------------- QKV projection ------------------------------------------
// Q is pre-scaled by 0.125*log2(e) so attention folds the softmax scale.
__global__ __launch_bounds__(256) void qkv_gemm(
    const bf16* __restrict__ xb, const bf16* __restrict__ Wt,
    const float* __restrict__ bq, const float* __restrict__ bk,
    const float* __restrict__ bv, bf16* __restrict__ Qb, bf16* __restrict__ Kb,
    bf16* __restrict__ Vt) {
  __shared__ __align__(128) char sA[16384];
  __shared__ __align__(128) char sB[16384];
  const int lane = threadIdx.x & 63, w = threadIdx.x >> 6;
  const int wr = w >> 1, wc = w & 1;
  const int rowA0 = blockIdx.y * 128;
  const int colB0 = blockIdx.x * 128;
  f32x4 acc[4][4];
  gemm_main(xb, Wt, rowA0, colB0, sA, sB, acc, wr, wc, lane, w);
  const int which = colB0 >> 9;
  const int cc0 = colB0 & 511;
  const float* bias = which == 0 ? bq : (which == 1 ? bk : bv);
  const float QSCALE = 0.18033688011112042f;  // 0.125 * log2(e)
#pragma unroll
  for (int m = 0; m < 4; m++)
#pragma unroll
    for (int n = 0; n < 4; n++)
#pragma unroll
      for (int r = 0; r < 4; r++) {
        int row = rowA0 + wr * 64 + m * 16 + (lane >> 4) * 4 + r;
        int col = cc0 + wc * 64 + n * 16 + (lane & 15);
        float v = acc[m][n][r] + bias[col];
        if (which == 0) {
          Qb[(int64_t)row * 512 + col] = (bf16)(v * QSCALE);
        } else if (which == 1) {
          Kb[(int64_t)row * 512 + col] = (bf16)v;
        } else {
          int b = row >> 12, nn = row & 4095;
          int hh = col >> 6, e = col & 63;
          Vt[(((int64_t)(b * 8 + hh)) * 64 + e) * 4096 + nn] = (bf16)v;
        }
      }
}

// ---------------- output projection (fp32 out) ----------------------------
__global__ __launch_bounds__(256) void out_gemm(const bf16* __restrict__ Ob,
                                                const bf16* __restrict__ Wpt,
                                                const float* __restrict__ bp,
                                                float* __restrict__ out) {
  __shared__ __align__(128) char sA[16384];
  __shared__ __align__(128) char sB[16384];
  const int lane = threadIdx.x & 63, w = threadIdx.x >> 6;
  const int wr = w >> 1, wc = w & 1;
  const int rowA0 = blockIdx.y * 128;
  const int colB0 = blockIdx.x * 128;
  f32x4 acc[4][4];
  gemm_main(Ob, Wpt, rowA0, colB0, sA, sB, acc, wr, wc, lane, w);
#pragma unroll
  for (int m = 0; m < 4; m++)
#pragma unroll
    for (int n = 0; n < 4; n++)
#pragma unroll
      for (int r = 0; r < 4; r++) {
        int row = rowA0 + wr * 64 + m * 16 + (lane >> 4) * 4 + r;
        int col = colB0 + wc * 64 + n * 16 + (lane & 15);
        out[(int64_t)row * 512 + col] = acc[m][n][r] + bp[col];
      }
}

// ---------------- fused flash attention: async-LDS 2-phase pipeline --------
// 512 thr = 8 waves = 2 heads x 4 q-subwaves (16 q-rows each; q-tile 64).
// KVBLK=32, K/V/coords double-buffered in LDS via global_load_lds; one
// barrier per tile; stage(i+1) issued before compute(i). Swapped QK^T.
// P buffer rows at 80B stride: conflict-free ds_write_b64 / ds_read_b128.
__global__ __launch_bounds__(512) void attn_kernel(
    const bf16* __restrict__ Qb, const bf16* __restrict__ Kb,
    const bf16* __restrict__ Vt, const float* __restrict__ coords,
    const float* __restrict__ slopes, bf16* __restrict__ Ob) {
  __shared__ __align__(128) char sK[2 * 8192];   // [buf][32 kv][256B: 2 heads]
  __shared__ __align__(128) char sV[2 * 10240];  // [buf][2 heads][64e][80B]
  __shared__ __align__(128) char sC[2 * 256];    // [buf][32 kv float2]
  __shared__ __align__(128) char sP[8 * 1280];   // per-wave P [16q][80B]

  const int tid = threadIdx.x;
  const int lane = tid & 63, w = tid >> 6;
  const int c = lane & 15, g = lane >> 4;

  const int id = blockIdx.x;       // 0..511
  const int combo = id & 7;        // -> XCD
  const int qt = id >> 3;          // 0..63
  const int b = combo >> 2, hp = combo & 3;  // head-pair 0..3
  const int q0 = qt * 64;
  const int qsub = w >> 1;         // 0..3
  const int hl = w & 1;            // head within pair
  const int h = hp * 2 + hl;
  const int qw = q0 + qsub * 16;
  const int bO = b * 4096;

  const float LOG2E = 1.4426950408889634f;
  const float negsl2 = -slopes[h] * LOG2E;

  // Q fragments (B-operand of swapped QK^T): lane holds Q[q=c][hd=g*8+j]
  bf16x8 aq[2];
  {
    int64_t base = ((int64_t)(bO + qw + c)) * 512 + h * 64 + g * 8;
    aq[0] = *(const bf16x8*)(Qb + base);
    aq[1] = *(const bf16x8*)(Qb + base + 32);
  }
  const float* cbf = coords + (int64_t)bO * 2;
  float qcx, qcy;
  {
    float2 qc = ((const float2*)cbf)[qw + c];
    qcx = qc.x;
    qcy = qc.y;
  }

  bf16x8 ones;
#pragma unroll
  for (int jj = 0; jj < 8; jj++) ones[jj] = (bf16)1.0f;

  float m2 = -1e30f;
  f32x4 o[4], osum;
#pragma unroll
  for (int n = 0; n < 4; n++) o[n] = (f32x4){0.f, 0.f, 0.f, 0.f};
  osum = (f32x4){0.f, 0.f, 0.f, 0.f};

  const bf16* Vbase = Vt + (int64_t)(b * 8 + hp * 2) * 64 * 4096;

  // -------- staging (zero-VGPR async) --------
  const int krr = w * 4 + (lane >> 4);
  const int kgs = (lane & 15) ^ (krr & 7);
  auto vstage = [&](int j, int kv0, char* dstb) {
    const int hj = j >= 5 ? 1 : 0;
    const int cj = j - hj * 5;
    const int G = cj * 64 + lane;          // 16B-granule id in head region
    const int row = (G * 52429) >> 18;     // G/5
    int gr = G - row * 5;
    if (gr > 3) gr = 0;                    // pad lane: harmless dup
    gload16(Vbase + (int64_t)hj * 262144 + row * 4096 + kv0 + gr * 8,
            dstb + hj * 5120 + cj * 1024);
  };
  auto STAGE = [&](int tile, int bb) {
    const int kv0 = tile * 32;
    gload16(Kb + (int64_t)(bO + kv0 + krr) * 512 + hp * 128 + kgs * 8,
            sK + bb * 8192 + w * 1024);
    vstage(w, kv0, sV + bb * 10240);
    if (w < 2) vstage(8 + w, kv0, sV + bb * 10240);
    if (w == 7) gload4(cbf + kv0 * 2 + lane, sC + bb * 256);
  };

  STAGE(0, 0);
  __syncthreads();

  char* pwv = sP + w * 1280;
  for (int tt = 0; tt < 128; ++tt) {
    const int bb = tt & 1;
    if (tt + 1 < 128) STAGE(tt + 1, bb ^ 1);

    const char* kb = sK + bb * 8192;
    const char* vb = sV + bb * 10240 + hl * 5120;
    const char* cbuf = sC + bb * 256;

    // S^T = (K Q^T): lane holds q=c, kv = 16t+4g+r, t in {0,1}
    bf16x8 kf[2][2];
#pragma unroll
    for (int t = 0; t < 2; t++)
#pragma unroll
      for (int kk = 0; kk < 2; kk++) {
        const int row = t * 16 + c;
        const int pg = (hl * 8 + kk * 4 + g) ^ (c & 7);
        kf[t][kk] = *(const bf16x8*)(kb + row * 256 + pg * 16);
      }
    float s[2][4];
    __builtin_amdgcn_s_setprio(1);
#pragma unroll
    for (int t = 0; t < 2; t++) {
      f32x4 sa = (f32x4){0.f, 0.f, 0.f, 0.f};
      sa = __builtin_amdgcn_mfma_f32_16x16x32_bf16(kf[t][0], aq[0], sa, 0, 0, 0);
      sa = __builtin_amdgcn_mfma_f32_16x16x32_bf16(kf[t][1], aq[1], sa, 0, 0, 0);
#pragma unroll
      for (int r = 0; r < 4; r++) s[t][r] = sa[r];
    }
    __builtin_amdgcn_s_setprio(0);

    // in-register bias from LDS-staged coords (broadcast reads).
    // Q is pre-scaled by 0.125*log2e, so s += negsl2 * dist is one fma.
#pragma unroll
    for (int t = 0; t < 2; t++) {
      f32x4 ca = *(const f32x4*)(cbuf + 128 * t + 32 * g);
      f32x4 cb = *(const f32x4*)(cbuf + 128 * t + 32 * g + 16);
      float dx, dy;
#define DIST1(T, R, CX, CY)                                              \
  dx = qcx - (CX);                                                       \
  dy = qcy - (CY);                                                       \
  s[T][R] = __builtin_fmaf(__builtin_amdgcn_sqrtf(dx * dx + dy * dy),    \
                           negsl2, s[T][R]);
      DIST1(t, 0, ca[0], ca[1])
      DIST1(t, 1, ca[2], ca[3])
      DIST1(t, 2, cb[0], cb[1])
      DIST1(t, 3, cb[2], cb[3])
#undef DIST1
    }

    // deferred online max (THR=8 base-2); row q=c lives on 4 g-lanes
    float lm = fmaxf(fmaxf(fmaxf(s[0][0], s[0][1]), fmaxf(s[0][2], s[0][3])),
                     fmaxf(fmaxf(s[1][0], s[1][1]), fmaxf(s[1][2], s[1][3])));
    lm = fmaxf(lm, __shfl_xor(lm, 16));
    lm = fmaxf(lm, __shfl_xor(lm, 32));
    if (__any(lm > m2 + 8.f)) {
      float nm = fmaxf(m2, lm);
      float sc = __builtin_amdgcn_exp2f(m2 - nm);
      m2 = nm;
      float scr[4];
#pragma unroll
      for (int r = 0; r < 4; r++)
        scr[r] = __shfl(sc, (lane & 48) | (4 * g + r));
#pragma unroll
      for (int n = 0; n < 4; n++)
#pragma unroll
        for (int r = 0; r < 4; r++) o[n][r] *= scr[r];
#pragma unroll
      for (int r = 0; r < 4; r++) osum[r] *= scr[r];
    }

    // P pack: [16q][32kv] bf16, 80B rows (conflict-free, no XOR needed)
#pragma unroll
    for (int t = 0; t < 2; t++) {
      bf16x4 pv = {(bf16)__builtin_amdgcn_exp2f(s[t][0] - m2),
                   (bf16)__builtin_amdgcn_exp2f(s[t][1] - m2),
                   (bf16)__builtin_amdgcn_exp2f(s[t][2] - m2),
                   (bf16)__builtin_amdgcn_exp2f(s[t][3] - m2)};
      const int L = 2 * t + (g >> 1);
      *(bf16x4*)(pwv + c * 80 + L * 16 + (g & 1) * 8) = pv;
    }
    bf16x8 pa = *(const bf16x8*)(pwv + c * 80 + g * 16);

    // PV + row-sum via ones-MFMA
    __builtin_amdgcn_s_setprio(1);
#pragma unroll
    for (int n = 0; n < 4; n++) {
      bf16x8 vf = *(const bf16x8*)(vb + (n * 16 + c) * 80 + g * 16);
      o[n] = __builtin_amdgcn_mfma_f32_16x16x32_bf16(pa, vf, o[n], 0, 0, 0);
    }
    osum = __builtin_amdgcn_mfma_f32_16x16x32_bf16(pa, ones, osum, 0, 0, 0);
    __builtin_amdgcn_s_setprio(0);

    __syncthreads();
  }

  // epilogue: normalize, store [b,n,d] bf16 (rows q = 4g+r)
#pragma unroll
  for (int r = 0; r < 4; r++) {
    float inv = 1.f / osum[r];
    int64_t row = (int64_t)bO + qw + g * 4 + r;
#pragma unroll
    for (int n = 0; n < 4; n++)
      Ob[row * 512 + h * 64 + n * 16 + c] = (bf16)(o[n][r] * inv);
  }
}

// ---------------- launch ---------------------------------------------------
extern "C" void kernel_launch(void* const* d_in, const int* in_sizes, int n_in,
                              void* d_out, int out_size, void* d_ws,
                              size_t ws_size, hipStream_t stream) {
  const float* x = (const float*)d_in[0];
  const float* coords = (const float*)d_in[1];
  const float* Wq = (const float*)d_in[2];
  const float* bq = (const float*)d_in[3];
  const float* Wk = (const float*)d_in[4];
  const float* bk = (const float*)d_in[5];
  const float* Wv = (const float*)d_in[6];
  const float* bv = (const float*)d_in[7];
  const float* Wp = (const float*)d_in[8];
  const float* bp = (const float*)d_in[9];
  const float* slopes = (const float*)d_in[10];

  char* ws = (char*)d_ws;
  bf16* xb = (bf16*)(ws);
  bf16* Wt = (bf16*)(ws + 8388608);
  bf16* Wpt = (bf16*)(ws + 9961472);
  bf16* Qb = (bf16*)(ws + 10485760);
  bf16* Kb = (bf16*)(ws + 18874368);
  bf16* Vt = (bf16*)(ws + 27262976);
  bf16* Ob = (bf16*)(ws + 35651584);

  hipLaunchKernelGGL(prep_kernel, dim3(1024), dim3(256), 0, stream, x, Wq, Wk,
                     Wv, Wp, xb, Wt, Wpt);
  hipLaunchKernelGGL(qkv_gemm, dim3(12, 64), dim3(256), 0, stream, xb, Wt, bq,
                     bk, bv, Qb, Kb, Vt);
  hipLaunchKernelGGL(attn_kernel, dim3(512), dim3(512), 0, stream, Qb, Kb,
                     Vt, coords, slopes, Ob);
  hipLaunchKernelGGL(out_gemm, dim3(4, 64), dim3(256), 0, stream, Ob, Wpt, bp,
                     (float*)d_out);
}

// Round 9
// 232.647 us; speedup vs baseline: 2.4394x; 1.0144x over previous
//
#include <hip/hip_runtime.h>
#include <stdint.h>

typedef __bf16 bf16;
typedef __attribute__((ext_vector_type(8))) __bf16 bf16x8;
typedef __attribute__((ext_vector_type(4))) __bf16 bf16x4;
typedef __attribute__((ext_vector_type(4))) float f32x4;

#define DEVFN static __device__ __forceinline__

DEVFN void gload16(const bf16* g, char* l) {
  __builtin_amdgcn_global_load_lds(
      (const __attribute__((address_space(1))) void*)g,
      (__attribute__((address_space(3))) void*)l, 16, 0, 0);
}
DEVFN void gload4(const float* g, char* l) {
  __builtin_amdgcn_global_load_lds(
      (const __attribute__((address_space(1))) void*)g,
      (__attribute__((address_space(3))) void*)l, 4, 0, 0);
}

DEVFN int swz(int row, int kb) { return row * 128 + (kb ^ ((row & 7) << 4)); }

#define PS 9437184LL  // partial stride per kv-split: 16 bh * 4096 q * 144 B

// ---------------- prep: fp32 -> bf16 + weight transposes --------------------
__global__ __launch_bounds__(256) void prep_kernel(
    const float* __restrict__ x, const float* __restrict__ Wq,
    const float* __restrict__ Wk, const float* __restrict__ Wv,
    const float* __restrict__ Wp, bf16* __restrict__ xb,
    bf16* __restrict__ Wt, bf16* __restrict__ Wpt) {
  const int64_t tid = blockIdx.x * 256LL + threadIdx.x;
  const int64_t stride = (int64_t)gridDim.x * 256LL;
  for (int64_t i = tid; i < (8192LL * 512) / 4; i += stride) {
    float4 v = ((const float4*)x)[i];
    bf16x4 o = {(bf16)v.x, (bf16)v.y, (bf16)v.z, (bf16)v.w};
    ((bf16x4*)xb)[i] = o;
  }
  for (int64_t i = tid; i < 1536LL * 512; i += stride) {
    int c = (int)(i >> 9), k = (int)(i & 511);
    int wsel = c >> 9, cc = c & 511;
    const float* W = wsel == 0 ? Wq : (wsel == 1 ? Wk : Wv);
    Wt[i] = (bf16)W[k * 512 + cc];
  }
  for (int64_t i = tid; i < 512LL * 512; i += stride) {
    int c = (int)(i >> 9), k = (int)(i & 511);
    Wpt[i] = (bf16)Wp[k * 512 + c];
  }
}

// ---------------- shared 128x128 bf16 GEMM mainloop (K=512, BK=64) ----------
DEVFN void gemm_main(const bf16* __restrict__ A, const bf16* __restrict__ B,
                     int rowA0, int rowB0, char* sA, char* sB, f32x4 acc[4][4],
                     int wr, int wc, int lane, int w) {
#pragma unroll
  for (int m = 0; m < 4; m++)
#pragma unroll
    for (int n = 0; n < 4; n++) acc[m][n] = (f32x4){0.f, 0.f, 0.f, 0.f};
  const int lr = lane >> 3;
  const int kswz = 8 * ((lane & 7) ^ lr);
  for (int k0 = 0; k0 < 512; k0 += 64) {
#pragma unroll
    for (int j = 0; j < 4; j++) {
      const int c = w * 4 + j;
      gload16(A + (rowA0 + c * 8 + lr) * 512 + k0 + kswz, sA + c * 1024);
      gload16(B + (rowB0 + c * 8 + lr) * 512 + k0 + kswz, sB + c * 1024);
    }
    __syncthreads();
    bf16x8 af[4][2], bfv[4][2];
#pragma unroll
    for (int m = 0; m < 4; m++)
#pragma unroll
      for (int kk = 0; kk < 2; kk++) {
        af[m][kk] = *(const bf16x8*)(sA + swz(wr * 64 + m * 16 + (lane & 15),
                                              kk * 64 + (lane >> 4) * 16));
        bfv[m][kk] = *(const bf16x8*)(sB + swz(wc * 64 + m * 16 + (lane & 15),
                                               kk * 64 + (lane >> 4) * 16));
      }
#pragma unroll
    for (int m = 0; m < 4; m++)
#pragma unroll
      for (int n = 0; n < 4; n++)
#pragma unroll
        for (int kk = 0; kk < 2; kk++)
          acc[m][n] = __builtin_amdgcn_mfma_f32_16x16x32_bf16(
              af[m][kk], bfv[n][kk], acc[m][n], 0, 0, 0);
    __syncthreads();
  }
}

// ---------------- QKV projection ------------------------------------------
// Q is pre-scaled by 0.125*log2(e) so attention folds the softmax scale.
__global__ __launch_bounds__(256) void qkv_gemm(
    const bf16* __restrict__ xb, const bf16* __restrict__ Wt,
    const float* __restrict__ bq, const float* __restrict__ bk,
    const float* __restrict__ bv, bf16* __restrict__ Qb, bf16* __restrict__ Kb,
    bf16* __restrict__ Vt) {
  __shared__ __align__(128) char sA[16384];
  __shared__ __align__(128) char sB[16384];
  const int lane = threadIdx.x & 63, w = threadIdx.x >> 6;
  const int wr = w >> 1, wc = w & 1;
  const int rowA0 = blockIdx.y * 128;
  const int colB0 = blockIdx.x * 128;
  f32x4 acc[4][4];
  gemm_main(xb, Wt, rowA0, colB0, sA, sB, acc, wr, wc, lane, w);
  const int which = colB0 >> 9;
  const int cc0 = colB0 & 511;
  const float* bias = which == 0 ? bq : (which == 1 ? bk : bv);
  const float QSCALE = 0.18033688011112042f;  // 0.125 * log2(e)
#pragma unroll
  for (int m = 0; m < 4; m++)
#pragma unroll
    for (int n = 0; n < 4; n++)
#pragma unroll
      for (int r = 0; r < 4; r++) {
        int row = rowA0 + wr * 64 + m * 16 + (lane >> 4) * 4 + r;
        int col = cc0 + wc * 64 + n * 16 + (lane & 15);
        float v = acc[m][n][r] + bias[col];
        if (which == 0) {
          Qb[(int64_t)row * 512 + col] = (bf16)(v * QSCALE);
        } else if (which == 1) {
          Kb[(int64_t)row * 512 + col] = (bf16)v;
        } else {
          int b = row >> 12, nn = row & 4095;
          int hh = col >> 6, e = col & 63;
          Vt[(((int64_t)(b * 8 + hh)) * 64 + e) * 4096 + nn] = (bf16)v;
        }
      }
}

// ---------------- output projection (fp32 out) ----------------------------
__global__ __launch_bounds__(256) void out_gemm(const bf16* __restrict__ Ob,
                                                const bf16* __restrict__ Wpt,
                                                const float* __restrict__ bp,
                                                float* __restrict__ out) {
  __shared__ __align__(128) char sA[16384];
  __shared__ __align__(128) char sB[16384];
  const int lane = threadIdx.x & 63, w = threadIdx.x >> 6;
  const int wr = w >> 1, wc = w & 1;
  const int rowA0 = blockIdx.y * 128;
  const int colB0 = blockIdx.x * 128;
  f32x4 acc[4][4];
  gemm_main(Ob, Wpt, rowA0, colB0, sA, sB, acc, wr, wc, lane, w);
#pragma unroll
  for (int m = 0; m < 4; m++)
#pragma unroll
    for (int n = 0; n < 4; n++)
#pragma unroll
      for (int r = 0; r < 4; r++) {
        int row = rowA0 + wr * 64 + m * 16 + (lane >> 4) * 4 + r;
        int col = colB0 + wc * 64 + n * 16 + (lane & 15);
        out[(int64_t)row * 512 + col] = acc[m][n][r] + bp[col];
      }
}

// ---------------- fused flash attention: async-LDS, kv-split --------------
// Block = 1 head, 8 waves = 8 q-subwaves (16 q each, q-tile 128), half the
// kv range (2048 = 64 tiles of KVBLK=32). Grid 1024 = exactly 4 blocks/CU,
// 32 waves/CU (max occupancy). K/V/coords double-buffered via
// global_load_lds; one barrier per tile. Swapped QK^T; partials
// (m2, osum, o bf16) written per q-row for the combine kernel.
// id = bh(4b) | qt(5b) | ks(1b): blocks of one bh land on one XCD (id%8).
__global__ __launch_bounds__(512) void attn_kernel(
    const bf16* __restrict__ Qb, const bf16* __restrict__ Kb,
    const bf16* __restrict__ Vt, const float* __restrict__ coords,
    const float* __restrict__ slopes, char* __restrict__ part) {
  __shared__ __align__(128) char sK[2 * 4096];  // [buf][32 kv][128B] swz
  __shared__ __align__(128) char sV[2 * 5120];  // [buf][64 e][80B]
  __shared__ __align__(128) char sC[2 * 256];   // [buf][32 kv float2]
  __shared__ __align__(128) char sP[8 * 1280];  // per-wave P [16q][80B]

  const int tid = threadIdx.x;
  const int lane = tid & 63, w = tid >> 6;
  const int c = lane & 15, g = lane >> 4;

  const int id = blockIdx.x;          // 0..1023
  const int bh = id & 15;             // bh%8 -> XCD
  const int qt = (id >> 4) & 31;
  const int ks = id >> 9;             // kv half
  const int b = bh >> 3, h = bh & 7;
  const int qw = qt * 128 + w * 16;
  const int bO = b * 4096;
  const int kvs = ks * 2048;

  const float LOG2E = 1.4426950408889634f;
  const float negsl2 = -slopes[h] * LOG2E;

  // Q fragments (B-operand of swapped QK^T): lane holds Q[q=c][hd=g*8+j]
  bf16x8 aq[2];
  {
    int64_t base = ((int64_t)(bO + qw + c)) * 512 + h * 64 + g * 8;
    aq[0] = *(const bf16x8*)(Qb + base);
    aq[1] = *(const bf16x8*)(Qb + base + 32);
  }
  const float* cbf = coords + (int64_t)bO * 2;
  float qcx, qcy;
  {
    float2 qc = ((const float2*)cbf)[qw + c];
    qcx = qc.x;
    qcy = qc.y;
  }

  bf16x8 ones;
#pragma unroll
  for (int jj = 0; jj < 8; jj++) ones[jj] = (bf16)1.0f;

  float m2 = -1e30f;
  f32x4 o[4], osum;
#pragma unroll
  for (int n = 0; n < 4; n++) o[n] = (f32x4){0.f, 0.f, 0.f, 0.f};
  osum = (f32x4){0.f, 0.f, 0.f, 0.f};

  const bf16* Kp = Kb + (int64_t)bO * 512 + h * 64;
  const bf16* Vp = Vt + (int64_t)(b * 8 + h) * 262144;

  // -------- staging (zero-VGPR async), 10 instrs over 8 waves --------
  auto vstage = [&](int j, int kv0, int bb) {
    const int G = j * 64 + lane;        // 16B-granule id (80B rows, G/5)
    const int row = (G * 52429) >> 18;  // G/5
    int gr = G - row * 5;
    if (gr > 3) gr = 0;                 // pad lane: harmless dup
    gload16(Vp + row * 4096 + kv0 + gr * 8, sV + bb * 5120 + j * 1024);
  };
  auto STAGE = [&](int tile, int bb) {
    const int kv0 = kvs + tile * 32;
    if (w < 4) {
      // K: [32][128B], granule phys = logical ^ (row&7); linear dest
      gload16(Kp + (int64_t)(kv0 + w * 8 + (lane >> 3)) * 512 +
                  ((lane & 7) ^ ((lane >> 3) & 7)) * 8,
              sK + bb * 4096 + w * 1024);
    } else {
      vstage(w - 4, kv0, bb);
    }
    if (w == 0) vstage(4, kv0, bb);
    if (w == 1) gload4(cbf + kv0 * 2 + lane, sC + bb * 256);
  };

  STAGE(0, 0);
  __syncthreads();

  char* pwv = sP + w * 1280;
  for (int tt = 0; tt < 64; ++tt) {
    const int bb = tt & 1;
    if (tt + 1 < 64) STAGE(tt + 1, bb ^ 1);

    const char* kb = sK + bb * 4096;
    const char* vb = sV + bb * 5120;
    const char* cbuf = sC + bb * 256;

    // S^T = (K Q^T): lane holds q=c, kv = 16t+4g+r, t in {0,1}
    bf16x8 kf[2][2];
#pragma unroll
    for (int t = 0; t < 2; t++)
#pragma unroll
      for (int kk = 0; kk < 2; kk++)
        kf[t][kk] = *(const bf16x8*)(kb + (t * 16 + c) * 128 +
                                     (((kk * 4 + g) ^ (c & 7)) * 16));
    float s[2][4];
    __builtin_amdgcn_s_setprio(1);
#pragma unroll
    for (int t = 0; t < 2; t++) {
      f32x4 sa = (f32x4){0.f, 0.f, 0.f, 0.f};
      sa = __builtin_amdgcn_mfma_f32_16x16x32_bf16(kf[t][0], aq[0], sa, 0, 0, 0);
      sa = __builtin_amdgcn_mfma_f32_16x16x32_bf16(kf[t][1], aq[1], sa, 0, 0, 0);
#pragma unroll
      for (int r = 0; r < 4; r++) s[t][r] = sa[r];
    }
    __builtin_amdgcn_s_setprio(0);

    // in-register bias from LDS-staged coords (broadcast reads)
#pragma unroll
    for (int t = 0; t < 2; t++) {
      f32x4 ca = *(const f32x4*)(cbuf + 128 * t + 32 * g);
      f32x4 cb2 = *(const f32x4*)(cbuf + 128 * t + 32 * g + 16);
      float dx, dy;
#define DIST1(T, R, CX, CY)                                              \
  dx = qcx - (CX);                                                       \
  dy = qcy - (CY);                                                       \
  s[T][R] = __builtin_fmaf(__builtin_amdgcn_sqrtf(dx * dx + dy * dy),    \
                           negsl2, s[T][R]);
      DIST1(t, 0, ca[0], ca[1])
      DIST1(t, 1, ca[2], ca[3])
      DIST1(t, 2, cb2[0], cb2[1])
      DIST1(t, 3, cb2[2], cb2[3])
#undef DIST1
    }

    // deferred online max (THR=8 base-2); row q=c lives on 4 g-lanes
    float lm = fmaxf(fmaxf(fmaxf(s[0][0], s[0][1]), fmaxf(s[0][2], s[0][3])),
                     fmaxf(fmaxf(s[1][0], s[1][1]), fmaxf(s[1][2], s[1][3])));
    lm = fmaxf(lm, __shfl_xor(lm, 16));
    lm = fmaxf(lm, __shfl_xor(lm, 32));
    if (__any(lm > m2 + 8.f)) {
      float nm = fmaxf(m2, lm);
      float sc = __builtin_amdgcn_exp2f(m2 - nm);
      m2 = nm;
      float scr[4];
#pragma unroll
      for (int r = 0; r < 4; r++)
        scr[r] = __shfl(sc, (lane & 48) | (4 * g + r));
#pragma unroll
      for (int n = 0; n < 4; n++)
#pragma unroll
        for (int r = 0; r < 4; r++) o[n][r] *= scr[r];
#pragma unroll
      for (int r = 0; r < 4; r++) osum[r] *= scr[r];
    }

    // P pack: [16q][32kv] bf16, 80B rows (conflict-free)
#pragma unroll
    for (int t = 0; t < 2; t++) {
      bf16x4 pv = {(bf16)__builtin_amdgcn_exp2f(s[t][0] - m2),
                   (bf16)__builtin_amdgcn_exp2f(s[t][1] - m2),
                   (bf16)__builtin_amdgcn_exp2f(s[t][2] - m2),
                   (bf16)__builtin_amdgcn_exp2f(s[t][3] - m2)};
      const int L = 2 * t + (g >> 1);
      *(bf16x4*)(pwv + c * 80 + L * 16 + (g & 1) * 8) = pv;
    }
    bf16x8 pa = *(const bf16x8*)(pwv + c * 80 + g * 16);

    // PV + row-sum via ones-MFMA
    __builtin_amdgcn_s_setprio(1);
#pragma unroll
    for (int n = 0; n < 4; n++) {
      bf16x8 vf = *(const bf16x8*)(vb + (n * 16 + c) * 80 + g * 16);
      o[n] = __builtin_amdgcn_mfma_f32_16x16x32_bf16(pa, vf, o[n], 0, 0, 0);
    }
    osum = __builtin_amdgcn_mfma_f32_16x16x32_bf16(pa, ones, osum, 0, 0, 0);
    __builtin_amdgcn_s_setprio(0);

    __syncthreads();
  }

  // epilogue: write partials {m2, osum, o[64] bf16} per q-row (144B rows)
  float m2r[4];
#pragma unroll
  for (int r = 0; r < 4; r++)
    m2r[r] = __shfl(m2, (lane & 48) | (4 * g + r));
  char* pb0 = part + ks * PS + ((int64_t)bh * 4096 + qw) * 144;
#pragma unroll
  for (int r = 0; r < 4; r++) {
    char* pb = pb0 + (g * 4 + r) * 144;
    if (c == 0) {
      *(float*)pb = m2r[r];
      *((float*)pb + 1) = osum[r];
    }
#pragma unroll
    for (int n = 0; n < 4; n++)
      *(bf16*)(pb + 16 + (n * 16 + c) * 2) = (bf16)o[n][r];
  }
}

// ---------------- combine: merge the 2 kv-split partials -> Ob -------------
__global__ __launch_bounds__(256) void combine_kernel(
    const char* __restrict__ part, bf16* __restrict__ Ob) {
  const int t = blockIdx.x * 256 + threadIdx.x;
  const int row = t >> 6;  // bh*4096 + q, 0..65535
  const int e = t & 63;
  const char* p0 = part + (int64_t)row * 144;
  const char* p1 = p0 + PS;
  const float m0 = *(const float*)p0, s0 = *((const float*)p0 + 1);
  const float m1 = *(const float*)p1, s1 = *((const float*)p1 + 1);
  const float o0 = (float)*(const bf16*)(p0 + 16 + e * 2);
  const float o1 = (float)*(const bf16*)(p1 + 16 + e * 2);
  const float m = fmaxf(m0, m1);
  const float w0 = __builtin_amdgcn_exp2f(m0 - m);
  const float w1 = __builtin_amdgcn_exp2f(m1 - m);
  const float res = (o0 * w0 + o1 * w1) / (s0 * w0 + s1 * w1);
  const int bh = row >> 12, q = row & 4095;
  Ob[((int64_t)((bh >> 3) * 4096 + q)) * 512 + (bh & 7) * 64 + e] = (bf16)res;
}

// ---------------- launch ---------------------------------------------------
extern "C" void kernel_launch(void* const* d_in, const int* in_sizes, int n_in,
                              void* d_out, int out_size, void* d_ws,
                              size_t ws_size, hipStream_t stream) {
  const float* x = (const float*)d_in[0];
  const float* coords = (const float*)d_in[1];
  const float* Wq = (const float*)d_in[2];
  const float* bq = (const float*)d_in[3];
  const float* Wk = (const float*)d_in[4];
  const float* bk = (const float*)d_in[5];
  const float* Wv = (const float*)d_in[6];
  const float* bv = (const float*)d_in[7];
  const float* Wp = (const float*)d_in[8];
  const float* bp = (const float*)d_in[9];
  const float* slopes = (const float*)d_in[10];

  char* ws = (char*)d_ws;
  bf16* xb = (bf16*)(ws);
  bf16* Wt = (bf16*)(ws + 8388608);
  bf16* Wpt = (bf16*)(ws + 9961472);
  bf16* Qb = (bf16*)(ws + 10485760);
  bf16* Kb = (bf16*)(ws + 18874368);
  bf16* Vt = (bf16*)(ws + 27262976);
  bf16* Ob = (bf16*)(ws + 35651584);
  char* part = ws + 44040192;  // 2 * PS = 18,874,368 B -> ends at ~62.9 MB

  hipLaunchKernelGGL(prep_kernel, dim3(1024), dim3(256), 0, stream, x, Wq, Wk,
                     Wv, Wp, xb, Wt, Wpt);
  hipLaunchKernelGGL(qkv_gemm, dim3(12, 64), dim3(256), 0, stream, xb, Wt, bq,
                     bk, bv, Qb, Kb, Vt);
  hipLaunchKernelGGL(attn_kernel, dim3(1024), dim3(512), 0, stream, Qb, Kb,
                     Vt, coords, slopes, part);
  hipLaunchKernelGGL(combine_kernel, dim3(16384), dim3(256), 0, stream, part,
                     Ob);
  hipLaunchKernelGGL(out_gemm, dim3(4, 64), dim3(256), 0, stream, Ob, Wpt, bp,
                     (float*)d_out);
}